// Round 9
// baseline (188.832 us; speedup 1.0000x reference)
//
#include <hip/hip_runtime.h>

#define HH 128
#define WW 128
#define CC 96
#define KK 7

#define SROWS 38                 // staged rows per tile: 32 out + 6 halo
#define BUF_F (SROWS * WW)       // 4864 floats = 19456 B per buffer
#define ZOFS_F (2 * BUF_F)       // zero row after the two buffers
#define LDS_F (ZOFS_F + WW)      // 9856 floats = 39424 B -> 4 blocks/CU

// Cross-tile pipelined morphological dilation (7x7 max-plus, zero-pad, ReLU
// folded). T3/T4 structure: one block = one (b,c) plane = one channel;
// 4 tiles (32-row quarters) per block, double-buffered LDS; stage of tile
// k+1 issued BEFORE compute of tile k; counted s_waitcnt vmcnt(5) (never 0
// in the loop) + raw s_barrier so the 5 in-flight staging loads span the
// whole compute phase. Uniform 5 global_load_lds per thread (40-slot stage,
// overflow rows 38/39 redirected to duplicate rows 36/37) makes the counted
// wait wave-uniform. A dedicated zero LDS row absorbs all padding: invalid
// strips (vertical OOB) and edge A/C windows (horizontal OOB) redirect
// their ds_read ADDRESS to it - no value selects, no zero-fix ds_writes.

typedef __attribute__((address_space(1))) const void gv_t;
typedef __attribute__((address_space(3))) void lv_t;

__device__ __forceinline__ void gload_lds16(const float* g, float* l) {
  // LDS dest = wave-uniform base + lane*16 (linear by construction).
  __builtin_amdgcn_global_load_lds((gv_t*)g, (lv_t*)(unsigned)(uintptr_t)l,
                                   16, 0, 0);
}

__global__ __launch_bounds__(256, 4) void morph_kernel(
    const float* __restrict__ x, const float* __restrict__ weight,
    float* __restrict__ out) {
  __shared__ float lds[LDS_F];
  const int t = threadIdx.x;
  const int wid = t >> 5;  // 32-lane group id 0..7 (stage row sub-id, rg)
  const int lid = t & 31;  // lane-in-group (stage col slot, cg)

  const int plane = blockIdx.x;  // b*CC + c
  const int c = plane % CC;
  const float* __restrict__ xp = x + (size_t)plane * (HH * WW);
  float* __restrict__ op = out + (size_t)plane * (HH * WW);
  const float* __restrict__ Wc = weight + c * (KK * KK);

  // 49 channel weights -> SGPRs (block-uniform).
  float wv[KK * KK];
#pragma unroll
  for (int k = 0; k < KK * KK; ++k)
    wv[k] = __int_as_float(__builtin_amdgcn_readfirstlane(__float_as_int(Wc[k])));

  float* const buf0 = &lds[0];
  float* const buf1 = &lds[BUF_F];
  float* const zp = &lds[ZOFS_F];

  if (t < 32) *(float4*)(zp + t * 4) = make_float4(0.f, 0.f, 0.f, 0.f);

  // Stage quarter qq into buffer lb: exactly 5 uniform loads per thread.
  // Rows 38/39 (slots beyond the 38-row buffer) redirect to rows 36/37 with
  // matching sources (benign duplicate writes, keeps vmcnt uniform at 5).
  // Vertical-OOB source rows are clamped; compute never reads those LDS rows
  // (it redirects invalid strips to the zero row instead).
#define STAGE(qq, lb)                                                        \
  do {                                                                       \
    _Pragma("unroll")                                                        \
    for (int kk = 0; kk < 5; ++kk) {                                         \
      int row_ = kk * 8 + wid; /* 0..39 */                                   \
      int srow_ = (row_ > 37) ? row_ - 2 : row_;                             \
      int grow_ = (qq) * 32 - 3 + srow_;                                     \
      grow_ = grow_ < 0 ? 0 : (grow_ > HH - 1 ? HH - 1 : grow_);             \
      gload_lds16(xp + grow_ * WW + lid * 4, (lb) + srow_ * WW + lid * 4);   \
    }                                                                        \
  } while (0)

  STAGE(0, buf0);
  __syncthreads();  // one-time drain: stage-0 + zero-row visible

  const int tc0 = lid << 2;  // first out col of this thread
  const int r0l = wid << 2;  // first out row within tile
  const bool lok = (tc0 >= 4);
  const bool rok = (tc0 <= WW - 8);

  for (int k = 0; k < 4; ++k) {  // 4 quarters of this plane
    float* const cur = (k & 1) ? buf1 : buf0;
    float* const nxt = (k & 1) ? buf0 : buf1;

    if (k < 3) {
      STAGE(k + 1, nxt);
      // Counted wait: everything older than the 5 just-issued staging loads
      // (i.e. stage k and all prior stores) is retired; stage k+1 stays in
      // flight across the barrier and the whole compute phase.
      asm volatile("s_waitcnt vmcnt(5)" ::: "memory");
    } else {
      asm volatile("s_waitcnt vmcnt(0)" ::: "memory");
    }
    __builtin_amdgcn_sched_barrier(0);
    __builtin_amdgcn_s_barrier();

    // ---- compute quarter k from cur ----
    float acc[4][4];
#pragma unroll
    for (int y = 0; y < 4; ++y)
#pragma unroll
      for (int q = 0; q < 4; ++q) acc[y][q] = 0.f;  // ReLU folded: start at 0

    const float* vb = cur + r0l * WW + tc0;  // strip s at vb + s*WW
    const int gq0 = k * 32 - 3 + r0l;        // global row of strip 0

    float4 S[2][3];  // 2-deep strip prefetch, static indexing
#define LOAD_STRIP(slot, s)                                                  \
    do {                                                                     \
      const bool rv_ = (unsigned)(gq0 + (s)) < (unsigned)HH;                 \
      const float* bs_ = rv_ ? (vb + (s) * WW) : zp;                         \
      const float* pA_ = (rv_ && lok) ? bs_ - 4 : zp;                        \
      const float* pC_ = (rv_ && rok) ? bs_ + 4 : zp;                        \
      S[slot][0] = *(const float4*)pA_;                                      \
      S[slot][1] = *(const float4*)bs_;                                      \
      S[slot][2] = *(const float4*)pC_;                                      \
    } while (0)

    LOAD_STRIP(0, 0);
#pragma unroll
    for (int s = 0; s < 10; ++s) {
      if (s + 1 < 10) LOAD_STRIP((s + 1) & 1, s + 1);
      const int sl = s & 1;
      const float4 A = S[sl][0], B = S[sl][1], C = S[sl][2];
      // e[m] = input col tc0-3+m (zeros arrive via the zero-row reads).
      const float e[10] = {A.y, A.z, A.w, B.x, B.y, B.z, B.w, C.x, C.y, C.z};

#pragma unroll
      for (int yl = 0; yl < 4; ++yl) {
        const int i = s - yl;            // weight row; folds at compile time
        if (i < 0 || i >= KK) continue;  // static guard (full unroll)
        const float w0 = wv[i * 7 + 0], w1 = wv[i * 7 + 1], w2 = wv[i * 7 + 2],
                    w3 = wv[i * 7 + 3], w4 = wv[i * 7 + 4], w5 = wv[i * 7 + 5],
                    w6 = wv[i * 7 + 6];
#pragma unroll
        for (int q = 0; q < 4; ++q) {
          const float t0 = e[q + 0] + w0;
          const float t1 = e[q + 1] + w1;
          const float t2 = e[q + 2] + w2;
          const float t3 = e[q + 3] + w3;
          const float t4 = e[q + 4] + w4;
          const float t5 = e[q + 5] + w5;
          const float t6 = e[q + 6] + w6;
          float m = acc[yl][q];
          m = fmaxf(fmaxf(m, t0), t1);  // fuses to v_max3_f32 (verified R4)
          m = fmaxf(fmaxf(m, t2), t3);
          m = fmaxf(fmaxf(m, t4), t5);
          acc[yl][q] = fmaxf(m, t6);
        }
      }

      if (s >= 6) {  // out row r0l + s - 6 complete
        const int yl = s - 6;
        *(float4*)(op + (size_t)(k * 32 + r0l + yl) * WW + tc0) =
            make_float4(acc[yl][0], acc[yl][1], acc[yl][2], acc[yl][3]);
      }
    }
#undef LOAD_STRIP

    // All LDS reads of cur retired before anyone re-stages into it (k+2).
    asm volatile("s_waitcnt lgkmcnt(0)" ::: "memory");
    __builtin_amdgcn_s_barrier();
    __builtin_amdgcn_sched_barrier(0);
  }
#undef STAGE
}

extern "C" void kernel_launch(void* const* d_in, const int* in_sizes, int n_in,
                              void* d_out, int out_size, void* d_ws, size_t ws_size,
                              hipStream_t stream) {
  const float* x = (const float*)d_in[0];
  const float* w = (const float*)d_in[1];
  float* out = (float*)d_out;
  // one block per (b,c) plane; 4 pipelined 32-row tiles per block
  const int nblocks = 16 * CC;
  morph_kernel<<<nblocks, 256, 0, stream>>>(x, w, out);
}